// Round 1
// baseline (65.777 us; speedup 1.0000x reference)
//
#include <hip/hip_runtime.h>

#define RCR 5.2f
#define RCA 3.5f
#define PI_F 3.14159265358979323846f

// TRIU[s1*4+s2] -> pair index (10 unordered species pairs)
__constant__ int c_triu[16] = {0,1,2,3, 1,4,5,6, 2,5,7,8, 3,6,8,9};

__global__ __launch_bounds__(64) void aev_kernel(
    const int* __restrict__ species,
    const float* __restrict__ coords,
    float* __restrict__ out,
    int NA)   // total atoms = N*64
{
    const int blk = blockIdx.x;
    const int n   = blk >> 6;   // molecule
    const int i   = blk & 63;   // center atom
    const int tid = threadIdx.x;

    __shared__ float sx[64], sy[64], sz[64];
    __shared__ int   ssp[64];
    __shared__ float dxs[64], dys[64], dzs[64], ds[64];
    __shared__ float aev[384];
    __shared__ int   nbr[64];
    __shared__ int   nbr_count;

    // stage molecule into LDS
    const float* c = coords + (size_t)(n * 64) * 3;
    sx[tid]  = c[tid * 3 + 0];
    sy[tid]  = c[tid * 3 + 1];
    sz[tid]  = c[tid * 3 + 2];
    ssp[tid] = species[n * 64 + tid];
    for (int f = tid; f < 384; f += 64) aev[f] = 0.0f;
    if (tid == 0) nbr_count = 0;
    __syncthreads();

    const float xi = sx[i], yi = sy[i], zi = sz[i];
    const float ddx = sx[tid] - xi;
    const float ddy = sy[tid] - yi;
    const float ddz = sz[tid] - zi;
    const float d2  = ddx * ddx + ddy * ddy + ddz * ddz;
    const float d   = sqrtf(d2);
    dxs[tid] = ddx; dys[tid] = ddy; dzs[tid] = ddz; ds[tid] = d;

    const bool isj = (tid != i);

    // ---- radial: lane j scatters its 16 shells into species slot ----
    if (isj && d <= RCR) {
        const float fc  = 0.5f * cosf((PI_F / RCR) * d) + 0.5f;
        const float pre = 0.25f * fc;
        const int   base = ssp[tid] * 16;
        #pragma unroll
        for (int r = 0; r < 16; r++) {
            const float t = d - (0.9f + 0.26875f * (float)r);
            atomicAdd(&aev[base + r], pre * expf(-16.0f * t * t));
        }
    }

    // ---- compact angular neighbor list ----
    if (isj && d <= RCA) {
        const int idx = atomicAdd(&nbr_count, 1);
        nbr[idx] = tid;
    }
    __syncthreads();

    // ---- angular: flattened j<k pair loop over neighbor list ----
    const int M = nbr_count;
    for (int q = tid; q < M * M; q += 64) {
        const int jj = q / M;
        const int kk = q - jj * M;
        if (kk <= jj) continue;
        const int j = nbr[jj], k = nbr[kk];
        const float dij = ds[j], dik = ds[k];
        const float dot = dxs[j] * dxs[k] + dys[j] * dys[k] + dzs[j] * dzs[k];
        float cosv = 0.95f * dot / (dij * dik);
        cosv = fminf(0.95f, fmaxf(-0.95f, cosv));
        const float theta = acosf(cosv);
        const float fcij  = 0.5f * cosf((PI_F / RCA) * dij) + 0.5f;
        const float fcik  = 0.5f * cosf((PI_F / RCA) * dik) + 0.5f;
        const float base2 = 2.0f * fcij * fcik;   // unordered pair = full weight
        const float davg  = 0.5f * (dij + dik);
        const int   pidx  = c_triu[ssp[j] * 4 + ssp[k]];
        float f2[4];
        #pragma unroll
        for (int a = 0; a < 4; a++) {
            const float t = davg - (0.9f + 0.65f * (float)a);
            f2[a] = base2 * expf(-8.0f * t * t);
        }
        float* dst = &aev[64 + pidx * 32];
        #pragma unroll
        for (int z = 0; z < 8; z++) {
            const float tz = (1.0f + cosf(theta - (PI_F / 16.0f) * (1.0f + 2.0f * (float)z))) * 0.5f;
            const float t2  = tz * tz;
            const float t4  = t2 * t2;
            const float t8  = t4 * t4;
            const float t16 = t8 * t8;
            const float t32 = t16 * t16;
            #pragma unroll
            for (int a = 0; a < 4; a++) {
                atomicAdd(&dst[a * 8 + z], f2[a] * t32);
            }
        }
    }
    __syncthreads();

    // ---- write out: species head, then this atom's 384 AEV values ----
    const int atom = n * 64 + i;
    if (tid == 0) out[atom] = (float)ssp[i];
    float* dstg = out + NA + (size_t)atom * 384;
    for (int f = tid; f < 384; f += 64) dstg[f] = aev[f];
}

extern "C" void kernel_launch(void* const* d_in, const int* in_sizes, int n_in,
                              void* d_out, int out_size, void* d_ws, size_t ws_size,
                              hipStream_t stream) {
    const int*   species = (const int*)d_in[0];
    const float* coords  = (const float*)d_in[1];
    float*       out     = (float*)d_out;
    const int NA = in_sizes[0];          // N * 64 atoms (1024)
    aev_kernel<<<NA, 64, 0, stream>>>(species, coords, out, NA);
}